// Round 5
// baseline (37051.898 us; speedup 1.0000x reference)
//
#include <hip/hip_runtime.h>
#include <hip/hip_bf16.h>

#define Bdim 32
#define Tdim 2048
#define Ddim 256
#define Hdim 256
#define Ldim 2
#define NWAVE 64          // waves (1-wave WGs) per layer
#define RING 16
#define BH (Bdim*Hdim)    // 8192

typedef short bf16x8 __attribute__((ext_vector_type(8)));
typedef float f32x4  __attribute__((ext_vector_type(4)));

#define MFMA16(a,b,c) __builtin_amdgcn_mfma_f32_16x16x32_bf16((a),(b),(c),0,0,0)

__device__ __forceinline__ short bf_bits(float f){
  __hip_bfloat16 h = __float2bfloat16(f);
  return (short)__builtin_bit_cast(unsigned short, h);
}
__device__ __forceinline__ float bf_f32(short s){
  return __builtin_bit_cast(float, ((unsigned)(unsigned short)s) << 16);
}
__device__ __forceinline__ void split_pair(float f, short& hi, short& lo){
  short h = bf_bits(f);
  lo = bf_bits(f - bf_f32(h));
  hi = h;
}
__device__ __forceinline__ float sigmoid_f(float x){ return 1.0f/(1.0f + __expf(-x)); }
__device__ __forceinline__ float tanh_f(float x){ return 1.0f - 2.0f/(__expf(2.0f*x) + 1.0f); }

// spin until all 64 per-wave flags for a (layer, t) are set
__device__ __forceinline__ void wait64(const int* p, int lane){
  while (true){
    int v = __hip_atomic_load(p + lane, __ATOMIC_ACQUIRE, __HIP_MEMORY_SCOPE_AGENT);
    if (__all(v != 0)) break;
    __builtin_amdgcn_s_sleep(2);
  }
}

__global__ void __launch_bounds__(64, 1)
lstm_persist(const float* __restrict__ x,
             const float* __restrict__ Wf, const float* __restrict__ bf,
             const float* __restrict__ Wi, const float* __restrict__ bi,
             const float* __restrict__ Wc, const float* __restrict__ bc,
             const float* __restrict__ Wo, const float* __restrict__ bo,
             float* __restrict__ out,
             int*   __restrict__ flags,      // [2][T][NWAVE]
             const float* __restrict__ zbuf, // BH zeros (h[-1])
             float* __restrict__ ring)       // [RING][BH] h0 ring
{
  const int lane  = threadIdx.x;
  const int bid   = blockIdx.x;
  const int layer = bid & 1;
  const int wid   = bid >> 1;        // 0..63 within layer
  const int wg    = wid >> 1;        // 0..31 col-slice (8 h-cols)
  const int mt    = wid & 1;         // row half (16 rows)

  const int l15 = lane & 15;
  const int kg  = lane >> 4;
  const bool lowhalf = (l15 < 8);
  const int mycol = wg*8 + (l15 & 7);
  const int row   = mt*16 + l15;     // A-row this lane supplies

  // ---------- cache weight B-fragments (hi/lo split) in VGPRs ----------
  // N-tile 0: cols 0..7 = f-gate, 8..15 = i-gate ; tile 1: c~-gate | o-gate
  const float* W0 = lowhalf ? Wf : Wi;
  const float* W1 = lowhalf ? Wc : Wo;
  const size_t wbase = (size_t)layer*(Ddim+Hdim)*Hdim + mycol;

  bf16x8 whi[2][16], wlo[2][16];
  #pragma unroll
  for (int nt=0; nt<2; ++nt){
    const float* Wp = nt ? W1 : W0;
    #pragma unroll
    for (int ks=0; ks<16; ++ks){
      bf16x8 h8, l8;
      #pragma unroll
      for (int j=0;j<8;++j){
        const int k = ks*32 + kg*8 + j;
        short hh, ll;
        split_pair(Wp[wbase + (size_t)k*Hdim], hh, ll);
        h8[j]=hh; l8[j]=ll;
      }
      whi[nt][ks]=h8; wlo[nt][ks]=l8;
    }
  }
  const float bias0 = (lowhalf ? bf : bi)[layer*Hdim + mycol];
  const float bias1 = (lowhalf ? bc : bo)[layer*Hdim + mycol];

  const float* xrow = x + (size_t)row*Tdim*Ddim;
  const size_t rowH = (size_t)row*Hdim;

  int* l0f = flags;                  // [T][NWAVE]
  int* l1f = flags + (size_t)Tdim*NWAVE;
  int* myf = layer ? l1f : l0f;

  float cst[4] = {0.f,0.f,0.f,0.f};
  float hv[4];

  for (int t=0; t<Tdim; ++t){
    // ---- dependency waits ----
    if (layer==0){
      if (t>0)     wait64(l0f + (size_t)(t-1)*NWAVE, lane);    // h0[t-1] ready
      if (t>=RING) wait64(l1f + (size_t)(t-RING)*NWAVE, lane); // ring slot free
    } else {
      wait64(l0f + (size_t)t*NWAVE, lane);                     // h0[t] ready
      if (t>0)     wait64(l1f + (size_t)(t-1)*NWAVE, lane);    // h1[t-1] ready
    }

    // ---- A-operand row pointers (comb = [part0 | part1]) ----
    const float* pa;
    const float* pb;
    if (layer==0){
      pa = xrow + (size_t)t*Ddim;
      pb = t ? (ring + (size_t)((t-1)&(RING-1))*BH + rowH) : (zbuf + rowH);
    } else {
      pa = ring + (size_t)(t&(RING-1))*BH + rowH;
      pb = t ? (out + (size_t)(t-1)*BH + rowH) : (zbuf + rowH);
    }

    f32x4 acc0 = {bias0,bias0,bias0,bias0};
    f32x4 acc1 = {bias1,bias1,bias1,bias1};

    #pragma unroll
    for (int ks=0; ks<16; ++ks){
      const float* p = (ks<8) ? (pa + (ks*32 + kg*8)) : (pb + ((ks-8)*32 + kg*8));
      const f32x4 u = *reinterpret_cast<const f32x4*>(p);
      const f32x4 v = *reinterpret_cast<const f32x4*>(p+4);
      bf16x8 ahi, alo;
      #pragma unroll
      for (int j=0;j<4;++j){
        short h,l;
        split_pair(u[j],h,l); ahi[j]=h;   alo[j]=l;
        split_pair(v[j],h,l); ahi[j+4]=h; alo[j+4]=l;
      }
      // 3-pass split product: ~fp32 accuracy
      acc0 = MFMA16(ahi, whi[0][ks], acc0);
      acc0 = MFMA16(alo, whi[0][ks], acc0);
      acc0 = MFMA16(ahi, wlo[0][ks], acc0);
      acc1 = MFMA16(ahi, whi[1][ks], acc1);
      acc1 = MFMA16(alo, whi[1][ks], acc1);
      acc1 = MFMA16(ahi, wlo[1][ks], acc1);
    }

    // ---- gates / state (lane pairs j <-> j+8 exchange f,c~ <-> i,o) ----
    #pragma unroll
    for (int r=0;r<4;++r){
      const float z0  = acc0[r], z1 = acc1[r];
      const float z0o = __shfl_xor(z0, 8, 64);
      const float z1o = __shfl_xor(z1, 8, 64);
      const float zf = lowhalf ? z0  : z0o;
      const float zi = lowhalf ? z0o : z0;
      const float zc = lowhalf ? z1  : z1o;
      const float zo = lowhalf ? z1o : z1;
      const float fg = sigmoid_f(zf);
      const float ig = sigmoid_f(zi) * tanh_f(zc);
      const float og = sigmoid_f(zo);
      const float cn = fg*cst[r] + ig;
      cst[r] = cn;
      hv[r]  = og + tanh_f(cn);   // faithful to reference: additive
    }

    // ---- write h slice ----
    float* hdst = layer ? (out + (size_t)t*BH) : (ring + (size_t)(t&(RING-1))*BH);
    if (lowhalf){
      #pragma unroll
      for (int r=0;r<4;++r)
        hdst[(size_t)(mt*16 + kg*4 + r)*Hdim + mycol] = hv[r];
      if (t == Tdim-1){
        float* hT = out + (size_t)Tdim*BH + (size_t)layer*BH;
        float* cT = hT + (size_t)Ldim*BH;
        #pragma unroll
        for (int r=0;r<4;++r){
          const size_t b = (size_t)(mt*16 + kg*4 + r);
          hT[b*Hdim + mycol] = hv[r];
          cT[b*Hdim + mycol] = cst[r];
        }
      }
    }

    __threadfence();  // flush h stores to device coherence point
    if (lane==0)
      __hip_atomic_store(myf + (size_t)t*NWAVE + wid, 1,
                         __ATOMIC_RELEASE, __HIP_MEMORY_SCOPE_AGENT);
  }
}

extern "C" void kernel_launch(void* const* d_in, const int* in_sizes, int n_in,
                              void* d_out, int out_size, void* d_ws, size_t ws_size,
                              hipStream_t stream)
{
  (void)in_sizes; (void)n_in; (void)out_size; (void)ws_size;
  const float* x  = (const float*)d_in[0];
  const float* Wf = (const float*)d_in[1];
  const float* bf = (const float*)d_in[2];
  const float* Wi = (const float*)d_in[3];
  const float* bi = (const float*)d_in[4];
  const float* Wc = (const float*)d_in[5];
  const float* bc = (const float*)d_in[6];
  const float* Wo = (const float*)d_in[7];
  const float* bo = (const float*)d_in[8];
  float* out = (float*)d_out;

  int*   flags = (int*)d_ws;                              // 2*T*64 ints = 2 MB
  float* zbuf  = (float*)d_ws + (size_t)2*Tdim*NWAVE;     // BH zeros = 32 KB
  float* ring  = zbuf + BH;                               // RING*BH floats = 512 KB

  const size_t zero_bytes = (size_t)2*Tdim*NWAVE*sizeof(int) + (size_t)BH*sizeof(float);
  hipMemsetAsync(d_ws, 0, zero_bytes, stream);            // flags + zero h(-1)

  lstm_persist<<<dim3(2*NWAVE), dim3(64), 0, stream>>>(
      x, Wf, bf, Wi, bi, Wc, bc, Wo, bo, out, flags, zbuf, ring);
}

// Round 6
// 26078.113 us; speedup vs baseline: 1.4208x; 1.4208x over previous
//
#include <hip/hip_runtime.h>
#include <hip/hip_bf16.h>

#define Bdim 32
#define Tdim 2048
#define Ddim 256
#define Hdim 256
#define Ldim 2
#define NWAVE 64          // waves (1-wave WGs) per layer
#define RING 16
#define BH (Bdim*Hdim)    // 8192

typedef short bf16x8 __attribute__((ext_vector_type(8)));
typedef float f32x4  __attribute__((ext_vector_type(4)));

#define MFMA16(a,b,c) __builtin_amdgcn_mfma_f32_16x16x32_bf16((a),(b),(c),0,0,0)

__device__ __forceinline__ short bf_bits(float f){
  __hip_bfloat16 h = __float2bfloat16(f);
  return (short)__builtin_bit_cast(unsigned short, h);
}
__device__ __forceinline__ float bf_f32(short s){
  return __builtin_bit_cast(float, ((unsigned)(unsigned short)s) << 16);
}
__device__ __forceinline__ void split_pair(float f, short& hi, short& lo){
  short h = bf_bits(f);
  lo = bf_bits(f - bf_f32(h));
  hi = h;
}
__device__ __forceinline__ float sigmoid_f(float x){ return 1.0f/(1.0f + __expf(-x)); }
__device__ __forceinline__ float tanh_f(float x){ return 1.0f - 2.0f/(__expf(2.0f*x) + 1.0f); }

// Per-access coherent ops (sc0 sc1: miss L1/L2, served by Infinity Cache).
// Relaxed => NO buffer_inv / buffer_wbl2 cache-wide maintenance.
__device__ __forceinline__ float cload(const float* p){
  return __hip_atomic_load(p, __ATOMIC_RELAXED, __HIP_MEMORY_SCOPE_SYSTEM);
}
__device__ __forceinline__ void cstore(float* p, float v){
  __hip_atomic_store(p, v, __ATOMIC_RELAXED, __HIP_MEMORY_SCOPE_SYSTEM);
}

// spin until the 32 cohort flags are set (lane&31 indexes; lanes 32-63 mirror)
__device__ __forceinline__ void wait32(const int* p, int lane){
  const int* q = p + (lane & 31);
  while (true){
    int v = __hip_atomic_load(q, __ATOMIC_RELAXED, __HIP_MEMORY_SCOPE_SYSTEM);
    if (__all(v != 0)) break;
    __builtin_amdgcn_s_sleep(2);
  }
  asm volatile("" ::: "memory");   // compile-order barrier: keep data loads after poll
}

__global__ void __launch_bounds__(64, 1)
lstm_persist(const float* __restrict__ x,
             const float* __restrict__ Wf, const float* __restrict__ bf,
             const float* __restrict__ Wi, const float* __restrict__ bi,
             const float* __restrict__ Wc, const float* __restrict__ bc,
             const float* __restrict__ Wo, const float* __restrict__ bo,
             float* __restrict__ out,
             int*   __restrict__ flags,      // [2][T][2(mt)][32(wg)]
             const float* __restrict__ zbuf, // BH zeros (h[-1])
             float* __restrict__ ring)       // [RING][BH] h0 ring
{
  const int lane  = threadIdx.x;
  const int bid   = blockIdx.x;
  const int layer = bid & 1;
  const int wid   = bid >> 1;        // 0..63 within layer
  const int wg    = wid >> 1;        // 0..31 col-slice (8 h-cols)
  const int mt    = wid & 1;         // row half (16 rows)

  const int l15 = lane & 15;
  const int kg  = lane >> 4;
  const bool lowhalf = (l15 < 8);
  const int mycol = wg*8 + (l15 & 7);
  const int row   = mt*16 + l15;     // A-row this lane supplies

  // ---------- cache weight B-fragments (hi/lo split) in VGPRs/AGPRs ----------
  // N-tile 0: cols 0..7 = f-gate, 8..15 = i-gate ; tile 1: c~-gate | o-gate
  const float* W0 = lowhalf ? Wf : Wi;
  const float* W1 = lowhalf ? Wc : Wo;
  const size_t wbase = (size_t)layer*(Ddim+Hdim)*Hdim + mycol;

  bf16x8 whi[2][16], wlo[2][16];
  #pragma unroll
  for (int nt=0; nt<2; ++nt){
    const float* Wp = nt ? W1 : W0;
    #pragma unroll
    for (int ks=0; ks<16; ++ks){
      bf16x8 h8, l8;
      #pragma unroll
      for (int j=0;j<8;++j){
        const int k = ks*32 + kg*8 + j;
        short hh, ll;
        split_pair(Wp[wbase + (size_t)k*Hdim], hh, ll);
        h8[j]=hh; l8[j]=ll;
      }
      whi[nt][ks]=h8; wlo[nt][ks]=l8;
    }
  }
  const float bias0 = (lowhalf ? bf : bi)[layer*Hdim + mycol];
  const float bias1 = (lowhalf ? bc : bo)[layer*Hdim + mycol];

  const float* xrow = x + (size_t)row*Tdim*Ddim;
  const size_t rowH = (size_t)row*Hdim;

  int* l0f = flags;                  // [T][2][32]
  int* l1f = flags + (size_t)Tdim*NWAVE;
  int* myf = layer ? l1f : l0f;

  float cst[4] = {0.f,0.f,0.f,0.f};
  float hv[4];

  for (int t=0; t<Tdim; ++t){
    // ---- dependency waits (32-wide: only the mt row-cohort) ----
    if (layer==0){
      if (t>0)     wait32(l0f + (size_t)(t-1)*NWAVE + mt*32, lane);    // h0[t-1] rows ready
      if (t>=RING) wait32(l1f + (size_t)(t-RING)*NWAVE + mt*32, lane); // ring slot consumed
    } else {
      wait32(l0f + (size_t)t*NWAVE + mt*32, lane);                     // h0[t] rows ready
      if (t>0)     wait32(l1f + (size_t)(t-1)*NWAVE + mt*32, lane);    // h1[t-1] rows ready
    }

    // ---- A-operand row pointers (comb = [part0 | part1]) ----
    const float* pa;
    const float* pb;
    if (layer==0){
      pa = xrow + (size_t)t*Ddim;
      pb = t ? (ring + (size_t)((t-1)&(RING-1))*BH + rowH) : (zbuf + rowH);
    } else {
      pa = ring + (size_t)(t&(RING-1))*BH + rowH;
      pb = t ? (out + (size_t)(t-1)*BH + rowH) : (zbuf + rowH);
    }

    f32x4 acc0 = {bias0,bias0,bias0,bias0};
    f32x4 acc1 = {bias1,bias1,bias1,bias1};

    #pragma unroll
    for (int ks=0; ks<16; ++ks){
      const float* p = (ks<8) ? (pa + (ks*32 + kg*8)) : (pb + ((ks-8)*32 + kg*8));
      // recurrent operands need per-access coherent loads; x is read-only (cached)
      const bool coh = (layer==1) || (ks>=8);
      float fv[8];
      if (coh){
        #pragma unroll
        for (int j=0;j<8;++j) fv[j] = cload(p+j);
      } else {
        const f32x4 u = *reinterpret_cast<const f32x4*>(p);
        const f32x4 v = *reinterpret_cast<const f32x4*>(p+4);
        #pragma unroll
        for (int j=0;j<4;++j){ fv[j]=u[j]; fv[j+4]=v[j]; }
      }
      bf16x8 ahi, alo;
      #pragma unroll
      for (int j=0;j<8;++j){
        short h,l;
        split_pair(fv[j],h,l); ahi[j]=h; alo[j]=l;
      }
      // 3-pass split product: ~fp32 accuracy
      acc0 = MFMA16(ahi, whi[0][ks], acc0);
      acc0 = MFMA16(alo, whi[0][ks], acc0);
      acc0 = MFMA16(ahi, wlo[0][ks], acc0);
      acc1 = MFMA16(ahi, whi[1][ks], acc1);
      acc1 = MFMA16(alo, whi[1][ks], acc1);
      acc1 = MFMA16(ahi, wlo[1][ks], acc1);
    }

    // ---- gates / state (lane pairs j <-> j+8 exchange f,c~ <-> i,o) ----
    #pragma unroll
    for (int r=0;r<4;++r){
      const float z0  = acc0[r], z1 = acc1[r];
      const float z0o = __shfl_xor(z0, 8, 64);
      const float z1o = __shfl_xor(z1, 8, 64);
      const float zf = lowhalf ? z0  : z0o;
      const float zi = lowhalf ? z0o : z0;
      const float zc = lowhalf ? z1  : z1o;
      const float zo = lowhalf ? z1o : z1;
      const float fg = sigmoid_f(zf);
      const float ig = sigmoid_f(zi) * tanh_f(zc);
      const float og = sigmoid_f(zo);
      const float cn = fg*cst[r] + ig;
      cst[r] = cn;
      hv[r]  = og + tanh_f(cn);   // faithful to reference: additive
    }

    // ---- write h slice (coherent, write-through to IC) ----
    float* hdst = layer ? (out + (size_t)t*BH) : (ring + (size_t)(t&(RING-1))*BH);
    if (lowhalf){
      #pragma unroll
      for (int r=0;r<4;++r)
        cstore(&hdst[(size_t)(mt*16 + kg*4 + r)*Hdim + mycol], hv[r]);
      if (t == Tdim-1){
        float* hT = out + (size_t)Tdim*BH + (size_t)layer*BH;
        float* cT = hT + (size_t)Ldim*BH;
        #pragma unroll
        for (int r=0;r<4;++r){
          const size_t b = (size_t)(mt*16 + kg*4 + r);
          hT[b*Hdim + mycol] = hv[r];
          cT[b*Hdim + mycol] = cst[r];
        }
      }
    }

    // order: data stores reach coherence point, THEN publish flag (no cache-wide ops)
    asm volatile("s_waitcnt vmcnt(0)" ::: "memory");
    if (lane==0)
      __hip_atomic_store(myf + (size_t)t*NWAVE + mt*32 + wg, 1,
                         __ATOMIC_RELAXED, __HIP_MEMORY_SCOPE_SYSTEM);
  }
}

extern "C" void kernel_launch(void* const* d_in, const int* in_sizes, int n_in,
                              void* d_out, int out_size, void* d_ws, size_t ws_size,
                              hipStream_t stream)
{
  (void)in_sizes; (void)n_in; (void)out_size; (void)ws_size;
  const float* x  = (const float*)d_in[0];
  const float* Wf = (const float*)d_in[1];
  const float* bf = (const float*)d_in[2];
  const float* Wi = (const float*)d_in[3];
  const float* bi = (const float*)d_in[4];
  const float* Wc = (const float*)d_in[5];
  const float* bc = (const float*)d_in[6];
  const float* Wo = (const float*)d_in[7];
  const float* bo = (const float*)d_in[8];
  float* out = (float*)d_out;

  int*   flags = (int*)d_ws;                              // 2*T*64 ints = 1 MB
  float* zbuf  = (float*)d_ws + (size_t)2*Tdim*NWAVE;     // BH zeros = 32 KB
  float* ring  = zbuf + BH;                               // RING*BH floats = 512 KB

  const size_t zero_bytes = (size_t)2*Tdim*NWAVE*sizeof(int) + (size_t)BH*sizeof(float);
  hipMemsetAsync(d_ws, 0, zero_bytes, stream);            // flags + zero h(-1)

  lstm_persist<<<dim3(2*NWAVE), dim3(64), 0, stream>>>(
      x, Wf, bf, Wi, bi, Wc, bc, Wo, bo, out, flags, zbuf, ring);
}

// Round 7
// 11016.611 us; speedup vs baseline: 3.3633x; 2.3672x over previous
//
#include <hip/hip_runtime.h>
#include <hip/hip_bf16.h>

#define Bdim 32
#define Tdim 2048
#define Ddim 256
#define Hdim 256
#define Ldim 2
#define NWAVE 64          // waves (1-wave WGs) per layer
#define RING 16
#define BH (Bdim*Hdim)    // 8192

typedef short bf16x8 __attribute__((ext_vector_type(8)));
typedef float f32x4  __attribute__((ext_vector_type(4)));

#define MFMA16(a,b,c) __builtin_amdgcn_mfma_f32_16x16x32_bf16((a),(b),(c),0,0,0)

__device__ __forceinline__ short bf_bits(float f){
  __hip_bfloat16 h = __float2bfloat16(f);
  return (short)__builtin_bit_cast(unsigned short, h);
}
__device__ __forceinline__ float bf_f32(short s){
  return __builtin_bit_cast(float, ((unsigned)(unsigned short)s) << 16);
}
__device__ __forceinline__ void split_pair(float f, short& hi, short& lo){
  short h = bf_bits(f);
  lo = bf_bits(f - bf_f32(h));
  hi = h;
}
__device__ __forceinline__ float sigmoid_f(float x){ return 1.0f/(1.0f + __expf(-x)); }
__device__ __forceinline__ float tanh_f(float x){ return 1.0f - 2.0f/(__expf(2.0f*x) + 1.0f); }

// Wide coherent load: 16B, bypasses L1/L2 (sc0 sc1), served by Infinity Cache.
// Non-atomic — freshness comes from issuing AFTER the flag poll; ordering into
// the consumer is enforced by an explicit s_waitcnt + sched_barrier (rule #18).
__device__ __forceinline__ f32x4 cload4(const float* p){
  f32x4 r;
  asm volatile("global_load_dwordx4 %0, %1, off sc0 sc1" : "=v"(r) : "v"(p));
  return r;
}
// Coherent scalar store (relaxed system-scope atomic: sc0 sc1, no cache-wide ops)
__device__ __forceinline__ void cstore(float* p, float v){
  __hip_atomic_store(p, v, __ATOMIC_RELAXED, __HIP_MEMORY_SCOPE_SYSTEM);
}

// Fused dual poll: lanes 0-31 watch pA[lane&31], lanes 32-63 watch pB[lane&31].
// Null pointer => that half is trivially satisfied.
__device__ __forceinline__ void waitBoth(const int* pA, const int* pB, int lane){
  const int* base = (lane & 32) ? pB : pA;
  const bool act  = (base != nullptr);
  const int* q    = act ? base + (lane & 31) : nullptr;
  while (true){
    int v = act ? __hip_atomic_load(q, __ATOMIC_RELAXED, __HIP_MEMORY_SCOPE_SYSTEM) : 1;
    if (__all(v != 0)) break;
    __builtin_amdgcn_s_sleep(1);
  }
  asm volatile("" ::: "memory");   // keep data loads after the poll
}

__global__ void __launch_bounds__(64, 1)
lstm_persist(const float* __restrict__ x,
             const float* __restrict__ Wf, const float* __restrict__ bf,
             const float* __restrict__ Wi, const float* __restrict__ bi,
             const float* __restrict__ Wc, const float* __restrict__ bc,
             const float* __restrict__ Wo, const float* __restrict__ bo,
             float* __restrict__ out,
             int*   __restrict__ flags,      // [2][T][2(mt)][32(wg)]
             const float* __restrict__ zbuf, // BH zeros (h[-1])
             float* __restrict__ ring)       // [RING][BH] h0 ring
{
  const int lane  = threadIdx.x;
  const int bid   = blockIdx.x;
  const int layer = bid & 1;
  const int wid   = bid >> 1;        // 0..63 within layer
  const int wg    = wid >> 1;        // 0..31 col-slice (8 h-cols)
  const int mt    = wid & 1;         // row half (16 rows)

  const int l15 = lane & 15;
  const int kg  = lane >> 4;
  const bool lowhalf = (l15 < 8);
  const int mycol = wg*8 + (l15 & 7);
  const int row   = mt*16 + l15;     // A-row this lane supplies

  // ---------- cache weight B-fragments (hi/lo split) in VGPRs/AGPRs ----------
  const float* W0 = lowhalf ? Wf : Wi;
  const float* W1 = lowhalf ? Wc : Wo;
  const size_t wbase = (size_t)layer*(Ddim+Hdim)*Hdim + mycol;

  bf16x8 whi[2][16], wlo[2][16];
  #pragma unroll
  for (int nt=0; nt<2; ++nt){
    const float* Wp = nt ? W1 : W0;
    #pragma unroll
    for (int ks=0; ks<16; ++ks){
      bf16x8 h8, l8;
      #pragma unroll
      for (int j=0;j<8;++j){
        const int k = ks*32 + kg*8 + j;
        short hh, ll;
        split_pair(Wp[wbase + (size_t)k*Hdim], hh, ll);
        h8[j]=hh; l8[j]=ll;
      }
      whi[nt][ks]=h8; wlo[nt][ks]=l8;
    }
  }
  const float bias0 = (lowhalf ? bf : bi)[layer*Hdim + mycol];
  const float bias1 = (lowhalf ? bc : bo)[layer*Hdim + mycol];

  const float* xrow = x + (size_t)row*Tdim*Ddim;
  const size_t rowH = (size_t)row*Hdim;

  int* l0f = flags;                  // [T][2][32]
  int* l1f = flags + (size_t)Tdim*NWAVE;
  int* myf = layer ? l1f : l0f;

  float cst[4] = {0.f,0.f,0.f,0.f};
  float hv[4];

  for (int t=0; t<Tdim; ++t){
    // ---- operand pointers (comb = [part0 | part1]) ----
    const float* pa;
    const float* pb;
    const int* wA; const int* wB;
    if (layer==0){
      pa = xrow + (size_t)t*Ddim;
      pb = t ? (ring + (size_t)((t-1)&(RING-1))*BH + rowH) : (zbuf + rowH);
      wA = t ? (l0f + (size_t)(t-1)*NWAVE + mt*32) : nullptr;          // h0[t-1]
      wB = (t>=RING) ? (l1f + (size_t)(t-RING)*NWAVE + mt*32) : nullptr; // ring free
    } else {
      pa = ring + (size_t)(t&(RING-1))*BH + rowH;
      pb = t ? (out + (size_t)(t-1)*BH + rowH) : (zbuf + rowH);
      wA = l0f + (size_t)t*NWAVE + mt*32;                               // h0[t]
      wB = t ? (l1f + (size_t)(t-1)*NWAVE + mt*32) : nullptr;           // h1[t-1]
    }

    f32x4 va[8], vb[8];   // pa data (k 0..255)
    f32x4 wa[8], wb[8];   // pb data (k 256..511)

    // layer-0: x loads are flag-independent — issue before the poll (hidden)
    if (layer==0){
      #pragma unroll
      for (int ks=0; ks<8; ++ks){
        const float* p = pa + ks*32 + kg*8;
        va[ks] = *reinterpret_cast<const f32x4*>(p);
        vb[ks] = *reinterpret_cast<const f32x4*>(p+4);
      }
    }

    waitBoth(wA, wB, lane);

    // coherent recurrent operands: all wide loads issued back-to-back
    if (layer==1){
      #pragma unroll
      for (int ks=0; ks<8; ++ks){
        const float* p = pa + ks*32 + kg*8;
        va[ks] = cload4(p);
        vb[ks] = cload4(p+4);
      }
    }
    #pragma unroll
    for (int ks=0; ks<8; ++ks){
      const float* p = pb + ks*32 + kg*8;
      wa[ks] = cload4(p);
      wb[ks] = cload4(p+4);
    }
    asm volatile("s_waitcnt vmcnt(0)" ::: "memory");
    __builtin_amdgcn_sched_barrier(0);

    f32x4 acc0 = {bias0,bias0,bias0,bias0};
    f32x4 acc1 = {bias1,bias1,bias1,bias1};

    #pragma unroll
    for (int ks=0; ks<16; ++ks){
      const f32x4 u = (ks<8) ? va[ks] : wa[ks-8];
      const f32x4 v = (ks<8) ? vb[ks] : wb[ks-8];
      bf16x8 ahi, alo;
      #pragma unroll
      for (int j=0;j<4;++j){
        short h,l;
        split_pair(u[j],h,l); ahi[j]=h;   alo[j]=l;
        split_pair(v[j],h,l); ahi[j+4]=h; alo[j+4]=l;
      }
      // 3-pass split product: ~fp32 accuracy
      acc0 = MFMA16(ahi, whi[0][ks], acc0);
      acc0 = MFMA16(alo, whi[0][ks], acc0);
      acc0 = MFMA16(ahi, wlo[0][ks], acc0);
      acc1 = MFMA16(ahi, whi[1][ks], acc1);
      acc1 = MFMA16(alo, whi[1][ks], acc1);
      acc1 = MFMA16(ahi, wlo[1][ks], acc1);
    }

    // ---- gates / state (lane pairs j <-> j+8 exchange f,c~ <-> i,o) ----
    #pragma unroll
    for (int r=0;r<4;++r){
      const float z0  = acc0[r], z1 = acc1[r];
      const float z0o = __shfl_xor(z0, 8, 64);
      const float z1o = __shfl_xor(z1, 8, 64);
      const float zf = lowhalf ? z0  : z0o;
      const float zi = lowhalf ? z0o : z0;
      const float zc = lowhalf ? z1  : z1o;
      const float zo = lowhalf ? z1o : z1;
      const float fg = sigmoid_f(zf);
      const float ig = sigmoid_f(zi) * tanh_f(zc);
      const float og = sigmoid_f(zo);
      const float cn = fg*cst[r] + ig;
      cst[r] = cn;
      hv[r]  = og + tanh_f(cn);   // faithful to reference: additive
    }

    // ---- write h slice (coherent, per-access — no cache-wide ops) ----
    float* hdst = layer ? (out + (size_t)t*BH) : (ring + (size_t)(t&(RING-1))*BH);
    if (lowhalf){
      #pragma unroll
      for (int r=0;r<4;++r)
        cstore(&hdst[(size_t)(mt*16 + kg*4 + r)*Hdim + mycol], hv[r]);
      if (t == Tdim-1){
        float* hT = out + (size_t)Tdim*BH + (size_t)layer*BH;
        float* cT = hT + (size_t)Ldim*BH;
        #pragma unroll
        for (int r=0;r<4;++r){
          const size_t b = (size_t)(mt*16 + kg*4 + r);
          hT[b*Hdim + mycol] = hv[r];
          cT[b*Hdim + mycol] = cst[r];
        }
      }
    }

    // order: data stores reach coherence point, THEN publish flag
    asm volatile("s_waitcnt vmcnt(0)" ::: "memory");
    if (lane==0)
      __hip_atomic_store(myf + (size_t)t*NWAVE + mt*32 + wg, 1,
                         __ATOMIC_RELAXED, __HIP_MEMORY_SCOPE_SYSTEM);
  }
}

extern "C" void kernel_launch(void* const* d_in, const int* in_sizes, int n_in,
                              void* d_out, int out_size, void* d_ws, size_t ws_size,
                              hipStream_t stream)
{
  (void)in_sizes; (void)n_in; (void)out_size; (void)ws_size;
  const float* x  = (const float*)d_in[0];
  const float* Wf = (const float*)d_in[1];
  const float* bf = (const float*)d_in[2];
  const float* Wi = (const float*)d_in[3];
  const float* bi = (const float*)d_in[4];
  const float* Wc = (const float*)d_in[5];
  const float* bc = (const float*)d_in[6];
  const float* Wo = (const float*)d_in[7];
  const float* bo = (const float*)d_in[8];
  float* out = (float*)d_out;

  int*   flags = (int*)d_ws;                              // 2*T*64 ints
  float* zbuf  = (float*)d_ws + (size_t)2*Tdim*NWAVE;     // BH zeros
  float* ring  = zbuf + BH;                               // RING*BH floats

  const size_t zero_bytes = (size_t)2*Tdim*NWAVE*sizeof(int) + (size_t)BH*sizeof(float);
  hipMemsetAsync(d_ws, 0, zero_bytes, stream);            // flags + zero h(-1)

  lstm_persist<<<dim3(2*NWAVE), dim3(64), 0, stream>>>(
      x, Wf, bf, Wi, bi, Wc, bc, Wo, bo, out, flags, zbuf, ring);
}

// Round 8
// 8979.784 us; speedup vs baseline: 4.1261x; 1.2268x over previous
//
#include <hip/hip_runtime.h>
#include <hip/hip_bf16.h>

#define Bdim 32
#define Tdim 2048
#define Ddim 256
#define Hdim 256
#define Ldim 2
#define NWAVE 64          // waves (1-wave WGs) per layer
#define RING 16
#define BH (Bdim*Hdim)    // 8192 elements per plane
#define R0SLOT (2*BH)     // hi+lo planes per ring0 slot (bf16 elems)

typedef short bf16x8 __attribute__((ext_vector_type(8)));
typedef float f32x4  __attribute__((ext_vector_type(4)));
typedef int   i32x4  __attribute__((ext_vector_type(4)));

#define MFMA16(a,b,c) __builtin_amdgcn_mfma_f32_16x16x32_bf16((a),(b),(c),0,0,0)

__device__ __forceinline__ short bf_bits(float f){
  __hip_bfloat16 h = __float2bfloat16(f);
  return (short)__builtin_bit_cast(unsigned short, h);
}
__device__ __forceinline__ float bf_f32(short s){
  return __builtin_bit_cast(float, ((unsigned)(unsigned short)s) << 16);
}
// RNE split (weights + producer h: quality where it matters)
__device__ __forceinline__ void split_pair(float f, short& hi, short& lo){
  short h = bf_bits(f);
  lo = bf_bits(f - bf_f32(h));
  hi = h;
}
// cheap truncation split (x path, per-step): total err ~2^-16 rel
__device__ __forceinline__ void tsplit(float f, short& hi, short& lo){
  unsigned u = __builtin_bit_cast(unsigned, f);
  hi = (short)(u >> 16);
  float r = __builtin_bit_cast(float, u & 0xffff0000u);
  lo = (short)(__builtin_bit_cast(unsigned, f - r) >> 16);
}
__device__ __forceinline__ float sigmoid_f(float x){ return 1.0f/(1.0f + __expf(-x)); }
__device__ __forceinline__ float tanh_f(float x){ return 1.0f - 2.0f/(__expf(2.0f*x) + 1.0f); }

// 16B coherent load (sc0 sc1: bypass L1/L2, served by IC) -> 8 bf16 fragment
__device__ __forceinline__ bf16x8 cload8bf(const unsigned short* p){
  i32x4 r;
  asm volatile("global_load_dwordx4 %0, %1, off sc0 sc1" : "=v"(r) : "v"(p));
  return __builtin_bit_cast(bf16x8, r);
}
// coherent 2B store (plane element)
__device__ __forceinline__ void cstore_bf(unsigned short* p, short v){
  asm volatile("global_store_short %0, %1, off sc0 sc1" :: "v"(p), "v"((int)v) : "memory");
}

// Fused dual poll: lanes 0-31 watch pA[lane&31], lanes 32-63 watch pB[lane&31].
__device__ __forceinline__ void waitBoth(const int* pA, const int* pB, int lane){
  const int* base = (lane & 32) ? pB : pA;
  const bool act  = (base != nullptr);
  const int* q    = act ? base + (lane & 31) : nullptr;
  while (true){
    int v = act ? __hip_atomic_load(q, __ATOMIC_RELAXED, __HIP_MEMORY_SCOPE_SYSTEM) : 1;
    if (__all(v != 0)) break;
    __builtin_amdgcn_s_sleep(1);
  }
  asm volatile("" ::: "memory");   // keep data loads after the poll
}

__global__ void __launch_bounds__(64, 1)
lstm_persist(const float* __restrict__ x,
             const float* __restrict__ Wf, const float* __restrict__ bf,
             const float* __restrict__ Wi, const float* __restrict__ bi,
             const float* __restrict__ Wc, const float* __restrict__ bc,
             const float* __restrict__ Wo, const float* __restrict__ bo,
             float* __restrict__ out,
             int*   __restrict__ flags,          // [2][T][2(mt)][32(wg)]
             unsigned short* __restrict__ zplane,// [2][BH] bf16 zeros
             unsigned short* __restrict__ ring0, // [RING][2][BH] h0 planes
             unsigned short* __restrict__ ring1) // [2][2][BH] h1 planes
{
  const int lane  = threadIdx.x;
  const int bid   = blockIdx.x;
  const int layer = bid & 1;
  const int wid   = bid >> 1;        // 0..63 within layer
  const int wg    = wid >> 1;        // 0..31 col-slice (8 h-cols)
  const int mt    = wid & 1;         // row half (16 rows)

  const int l15 = lane & 15;
  const int kg  = lane >> 4;
  const bool lowhalf = (l15 < 8);
  const int mycol = wg*8 + (l15 & 7);
  const int row   = mt*16 + l15;     // A-row this lane supplies

  // ---------- cache weight B-fragments (hi/lo RNE split) in regs ----------
  const float* W0 = lowhalf ? Wf : Wi;
  const float* W1 = lowhalf ? Wc : Wo;
  const size_t wbase = (size_t)layer*(Ddim+Hdim)*Hdim + mycol;

  bf16x8 whi[2][16], wlo[2][16];
  #pragma unroll
  for (int nt=0; nt<2; ++nt){
    const float* Wp = nt ? W1 : W0;
    #pragma unroll
    for (int ks=0; ks<16; ++ks){
      bf16x8 h8, l8;
      #pragma unroll
      for (int j=0;j<8;++j){
        const int k = ks*32 + kg*8 + j;
        short hh, ll;
        split_pair(Wp[wbase + (size_t)k*Hdim], hh, ll);
        h8[j]=hh; l8[j]=ll;
      }
      whi[nt][ks]=h8; wlo[nt][ks]=l8;
    }
  }
  const float bias0 = (lowhalf ? bf : bi)[layer*Hdim + mycol];
  const float bias1 = (lowhalf ? bc : bo)[layer*Hdim + mycol];

  const float* xrow = x + (size_t)row*Tdim*Ddim;
  const size_t rowH = (size_t)row*Hdim;   // offset within a plane

  int* l0f = flags;                  // [T][2][32]
  int* l1f = flags + (size_t)Tdim*NWAVE;
  int* myf = layer ? l1f : l0f;

  float cst[4] = {0.f,0.f,0.f,0.f};
  float hv[4];

  for (int t=0; t<Tdim; ++t){
    // ---- pointers ----
    const unsigned short *pah, *pal;   // A-part planes (layer1) ; layer0 uses x
    const unsigned short *pbh, *pbl;   // B-part planes
    const float* pax = nullptr;
    const int *wA, *wB;
    if (layer==0){
      pax = xrow + (size_t)t*Ddim;
      if (t){
        const unsigned short* s = ring0 + (size_t)((t-1)&(RING-1))*R0SLOT + rowH;
        pbh = s; pbl = s + BH;
      } else { pbh = zplane + rowH; pbl = zplane + BH + rowH; }
      wA = t ? (l0f + (size_t)(t-1)*NWAVE + mt*32) : nullptr;            // h0[t-1]
      wB = (t>=RING) ? (l1f + (size_t)(t-RING)*NWAVE + mt*32) : nullptr; // ring free
      pah = pal = nullptr;
    } else {
      const unsigned short* a = ring0 + (size_t)(t&(RING-1))*R0SLOT + rowH;
      pah = a; pal = a + BH;
      if (t){
        const unsigned short* s = ring1 + (size_t)((t-1)&1)*R0SLOT + rowH;
        pbh = s; pbl = s + BH;
      } else { pbh = zplane + rowH; pbl = zplane + BH + rowH; }
      wA = l0f + (size_t)t*NWAVE + mt*32;                                // h0[t]
      wB = t ? (l1f + (size_t)(t-1)*NWAVE + mt*32) : nullptr;            // h1[t-1]
    }

    bf16x8 Ah[8], Al[8], Bh[8], Bl[8];
    f32x4 xu[8], xv[8];

    // layer-0: x loads are flag-independent — issue before the poll
    if (layer==0){
      #pragma unroll
      for (int ks=0; ks<8; ++ks){
        const float* p = pax + ks*32 + kg*8;
        xu[ks] = *reinterpret_cast<const f32x4*>(p);
        xv[ks] = *reinterpret_cast<const f32x4*>(p+4);
      }
    }

    waitBoth(wA, wB, lane);

    // coherent plane loads: MFMA-ready fragments, no conversion needed
    if (layer==1){
      #pragma unroll
      for (int ks=0; ks<8; ++ks){
        Ah[ks] = cload8bf(pah + ks*32 + kg*8);
        Al[ks] = cload8bf(pal + ks*32 + kg*8);
      }
    }
    #pragma unroll
    for (int ks=0; ks<8; ++ks){
      Bh[ks] = cload8bf(pbh + ks*32 + kg*8);
      Bl[ks] = cload8bf(pbl + ks*32 + kg*8);
    }
    asm volatile("s_waitcnt vmcnt(0)" ::: "memory");
    __builtin_amdgcn_sched_barrier(0);

    // layer-0: split x into fragments (cheap trunc split)
    if (layer==0){
      #pragma unroll
      for (int ks=0; ks<8; ++ks){
        bf16x8 h8, l8;
        #pragma unroll
        for (int j=0;j<4;++j){
          short h,l;
          tsplit(xu[ks][j],h,l); h8[j]=h;   l8[j]=l;
          tsplit(xv[ks][j],h,l); h8[j+4]=h; l8[j+4]=l;
        }
        Ah[ks]=h8; Al[ks]=l8;
      }
    }

    f32x4 acc0 = {bias0,bias0,bias0,bias0};
    f32x4 acc1 = {bias1,bias1,bias1,bias1};

    #pragma unroll
    for (int ks=0; ks<16; ++ks){
      const bf16x8 ah = (ks<8) ? Ah[ks] : Bh[ks-8];
      const bf16x8 al = (ks<8) ? Al[ks] : Bl[ks-8];
      // 3-pass split product: ~fp32 accuracy
      acc0 = MFMA16(ah, whi[0][ks], acc0);
      acc0 = MFMA16(al, whi[0][ks], acc0);
      acc0 = MFMA16(ah, wlo[0][ks], acc0);
      acc1 = MFMA16(ah, whi[1][ks], acc1);
      acc1 = MFMA16(al, whi[1][ks], acc1);
      acc1 = MFMA16(ah, wlo[1][ks], acc1);
    }

    // ---- gates / state (lane pairs j <-> j+8 exchange f,c~ <-> i,o) ----
    #pragma unroll
    for (int r=0;r<4;++r){
      const float z0  = acc0[r], z1 = acc1[r];
      const float z0o = __shfl_xor(z0, 8, 64);
      const float z1o = __shfl_xor(z1, 8, 64);
      const float zf = lowhalf ? z0  : z0o;
      const float zi = lowhalf ? z0o : z0;
      const float zc = lowhalf ? z1  : z1o;
      const float zo = lowhalf ? z1o : z1;
      const float fg = sigmoid_f(zf);
      const float ig = sigmoid_f(zi) * tanh_f(zc);
      const float og = sigmoid_f(zo);
      const float cn = fg*cst[r] + ig;
      cst[r] = cn;
      hv[r]  = og + tanh_f(cn);   // faithful to reference: additive
    }

    // ---- producer-side split + plane stores (both halves work in parallel) ----
    {
      unsigned short* base = layer ? (ring1 + (size_t)(t&1)*R0SLOT)
                                   : (ring0 + (size_t)(t&(RING-1))*R0SLOT);
      unsigned short* myplane = lowhalf ? base : base + BH;  // hi | lo
      #pragma unroll
      for (int r=0;r<4;++r){
        short h,l; split_pair(hv[r],h,l);
        const short v = lowhalf ? h : l;
        cstore_bf(&myplane[(size_t)(mt*16 + kg*4 + r)*Hdim + mycol], v);
      }
      if (layer==1 && lowhalf){
        #pragma unroll
        for (int r=0;r<4;++r)
          out[(size_t)t*BH + (size_t)(mt*16 + kg*4 + r)*Hdim + mycol] = hv[r];
      }
      if (t == Tdim-1 && lowhalf){
        float* hT = out + (size_t)Tdim*BH + (size_t)layer*BH;
        float* cT = hT + (size_t)Ldim*BH;
        #pragma unroll
        for (int r=0;r<4;++r){
          const size_t b = (size_t)(mt*16 + kg*4 + r);
          hT[b*Hdim + mycol] = hv[r];
          cT[b*Hdim + mycol] = cst[r];
        }
      }
    }

    // order: plane stores reach coherence point, THEN publish flag
    asm volatile("s_waitcnt vmcnt(0)" ::: "memory");
    if (lane==0)
      __hip_atomic_store(myf + (size_t)t*NWAVE + mt*32 + wg, 1,
                         __ATOMIC_RELAXED, __HIP_MEMORY_SCOPE_SYSTEM);
  }
}

extern "C" void kernel_launch(void* const* d_in, const int* in_sizes, int n_in,
                              void* d_out, int out_size, void* d_ws, size_t ws_size,
                              hipStream_t stream)
{
  (void)in_sizes; (void)n_in; (void)out_size; (void)ws_size;
  const float* x  = (const float*)d_in[0];
  const float* Wf = (const float*)d_in[1];
  const float* bf = (const float*)d_in[2];
  const float* Wi = (const float*)d_in[3];
  const float* bi = (const float*)d_in[4];
  const float* Wc = (const float*)d_in[5];
  const float* bc = (const float*)d_in[6];
  const float* Wo = (const float*)d_in[7];
  const float* bo = (const float*)d_in[8];
  float* out = (float*)d_out;

  int* flags = (int*)d_ws;                                   // 2*T*64 ints = 1 MB
  unsigned short* zplane = (unsigned short*)(flags + (size_t)2*Tdim*NWAVE); // 2*BH bf16
  unsigned short* ring0  = zplane + (size_t)2*BH;            // RING*2*BH bf16
  unsigned short* ring1  = ring0 + (size_t)RING*R0SLOT;      // 2*2*BH bf16

  const size_t zero_bytes = (size_t)2*Tdim*NWAVE*sizeof(int)
                          + (size_t)2*BH*sizeof(unsigned short);
  hipMemsetAsync(d_ws, 0, zero_bytes, stream);               // flags + zero planes

  lstm_persist<<<dim3(2*NWAVE), dim3(64), 0, stream>>>(
      x, Wf, bf, Wi, bi, Wc, bc, Wo, bo, out, flags, zplane, ring0, ring1);
}